// Round 1
// baseline (462.495 us; speedup 1.0000x reference)
//
#include <hip/hip_runtime.h>

typedef unsigned short u16;
typedef unsigned int u32;
typedef __attribute__((ext_vector_type(8))) short short8;
typedef __attribute__((ext_vector_type(4))) float f32x4;

__device__ __forceinline__ u16 f2bf(float f) {
    u32 u = __float_as_uint(f);
    return (u16)((u + 0x7FFFu + ((u >> 16) & 1u)) >> 16);
}

// ---------------------------------------------------------------------------
// Kernel 0a: NCHW fp32 -> NHWC bf16  (x[32][256][4096] -> xb[32][4096][256])
// 64ic x 64px tile per block via padded LDS; coalesced read + coalesced write.
// ---------------------------------------------------------------------------
__global__ __launch_bounds__(256) void nchw2nhwc(const float* __restrict__ x,
                                                 u16* __restrict__ xb) {
    __shared__ float tile[64][65];
    const int b   = blockIdx.x;
    const int n   = b >> 8;          // 32 images
    const int icb = (b >> 6) & 3;    // 4 blocks of 64 ic
    const int pxb = b & 63;          // 64 blocks of 64 px
    const int ic0 = icb * 64, px0 = pxb * 64;

    const int g = threadIdx.x >> 6, lx = threadIdx.x & 63;
    const float* src = x + (size_t)(n * 256 + ic0) * 4096 + px0 + lx;
#pragma unroll
    for (int r = 0; r < 16; ++r) {
        int row = g * 16 + r;
        tile[row][lx] = src[(size_t)row * 4096];
    }
    __syncthreads();
    const int tp = threadIdx.x & 31, pz = threadIdx.x >> 5;
    u16* dst = xb + ((size_t)(n * 4096) + px0) * 256 + ic0 + tp * 2;
#pragma unroll
    for (int r = 0; r < 8; ++r) {
        int p = pz * 8 + r;
        u32 pv = ((u32)f2bf(tile[tp * 2 + 1][p]) << 16) | f2bf(tile[tp * 2][p]);
        *(u32*)(dst + (size_t)p * 256) = pv;
    }
}

// ---------------------------------------------------------------------------
// Kernel 0b: hypernet weight generation -> bf16 weights
// wb layout: [oc][icb(8)][tap(9)][icw(32)]  (flat K = (icb*9+tap)*32 + icw)
// per block l (256 blocks): a = W1@z + B1 (16x64); K = W2@a + B2 (16x144)
// weight[ob*16+b2][ib*16+b1][kh][kw] = K[l][b1][b2*9+kh*3+kw]
// ---------------------------------------------------------------------------
__global__ __launch_bounds__(256) void wgen(const float* __restrict__ z,
                                            const float* __restrict__ W1,
                                            const float* __restrict__ B1,
                                            const float* __restrict__ W2,
                                            const float* __restrict__ B2,
                                            u16* __restrict__ wb) {
    __shared__ float zl[64];
    __shared__ float aL[1024];
    const int l = blockIdx.x;
    const int tid = threadIdx.x;
    if (tid < 64) zl[tid] = z[l * 64 + tid];
    __syncthreads();
#pragma unroll
    for (int i = 0; i < 4; ++i) {
        int idx = i * 256 + tid;            // = b*64 + d
        const float* wrow = W1 + (size_t)idx * 64;
        float s = B1[idx];
        for (int nn = 0; nn < 64; ++nn) s += wrow[nn] * zl[nn];
        aL[idx] = s;
    }
    __syncthreads();
    const int b1 = tid >> 4, b2 = tid & 15;
    const int ob = l >> 4, ib = l & 15;
    const int ic = ib * 16 + b1;
    const int oc = ob * 16 + b2;
    const size_t wbase = (size_t)oc * 2304 + (size_t)(ic >> 5) * 288 + (ic & 31);
    const float* arow = aL + b1 * 64;
#pragma unroll
    for (int tap = 0; tap < 9; ++tap) {
        int kk = b2 * 9 + tap;
        const float* w2row = W2 + (size_t)(b1 * 144 + kk) * 64;
        float s = B2[b1 * 144 + kk];
        for (int d = 0; d < 64; ++d) s += w2row[d] * arow[d];
        wb[wbase + tap * 32] = f2bf(s);
    }
}

// ---------------------------------------------------------------------------
// Kernel 1: implicit-GEMM conv. M=oc(256) N=pixels(131072) K=2304.
// Block: 128x128 tile, 4 waves, each 64x64 via 4x4 MFMA 16x16x32 bf16.
// K-iter kt = icb*9 + tap; tap shift = column offset in flat NHWC pixel space,
// boundary-masked (zero) at staging time.
// ---------------------------------------------------------------------------
__global__ __launch_bounds__(256) void conv_mfma(const u16* __restrict__ xb,
                                                 const u16* __restrict__ wb,
                                                 float* __restrict__ out) {
    __shared__ __align__(16) u16 As[128 * 32];   // [oc_r][k]   8 KB
    __shared__ __align__(16) u16 Bs[128 * 32];   // [col][ic]   8 KB

    const int tid = threadIdx.x;
    const int bid = blockIdx.x;
    const int mt = bid & 1;              // oc tile: 0/1
    const int nt = bid >> 1;             // pixel tile: 0..1023
    const int n = nt >> 5;               // image
    const int pimg = (nt & 31) << 7;     // pixel-in-image base (2 rows)
    const int oc0 = mt << 7;

    const int lane = tid & 63;
    const int wave = tid >> 6;
    const int wm = (wave >> 1) & 1, wn = wave & 1;
    const int lr = lane & 15, lq = lane >> 4;

    // staging decomposition: chunks q in {tid, tid+256}; r=q>>2 (row/col), cx=q&3
    const int qa = tid, qb = tid + 256;
    const int r0 = qa >> 2, c0 = qa & 3;
    const int r1 = qb >> 2, c1 = qb & 3;

    const u16* aw0 = wb + (size_t)(oc0 + r0) * 2304 + c0 * 8;
    const u16* aw1 = wb + (size_t)(oc0 + r1) * 2304 + c1 * 8;
    u16* asw0 = As + r0 * 32 + c0 * 8;
    u16* asw1 = As + r1 * 32 + c1 * 8;

    const int po0 = pimg + r0, po1 = pimg + r1;      // output pixel per B chunk
    const int ho0 = po0 >> 6, wo0 = po0 & 63;
    const int ho1 = po1 >> 6, wo1 = po1 & 63;
    const u16* bx0 = xb + ((size_t)n * 4096 + po0) * 256 + c0 * 8;
    const u16* bx1 = xb + ((size_t)n * 4096 + po1) * 256 + c1 * 8;
    u16* bsw0 = Bs + r0 * 32 + c0 * 8;
    u16* bsw1 = Bs + r1 * 32 + c1 * 8;

    f32x4 acc[4][4];
    const f32x4 z4 = {0.f, 0.f, 0.f, 0.f};
#pragma unroll
    for (int i = 0; i < 4; ++i)
#pragma unroll
        for (int j = 0; j < 4; ++j) acc[i][j] = z4;

    int icb = 0, tap = 0;
    for (int kt = 0; kt < 72; ++kt) {
        const int dh = tap / 3 - 1, dw = tap % 3 - 1;
        const int goff = (dh * 64 + dw) * 256 + icb * 32;  // elem offset into xb
        const int aoffk = kt * 32;

        uint4 av0 = *(const uint4*)(aw0 + aoffk);
        uint4 av1 = *(const uint4*)(aw1 + aoffk);
        uint4 bv0 = {0, 0, 0, 0}, bv1 = {0, 0, 0, 0};
        {
            int hi = ho0 + dh, wi = wo0 + dw;
            if ((unsigned)hi < 64u && (unsigned)wi < 64u)
                bv0 = *(const uint4*)(bx0 + goff);
        }
        {
            int hi = ho1 + dh, wi = wo1 + dw;
            if ((unsigned)hi < 64u && (unsigned)wi < 64u)
                bv1 = *(const uint4*)(bx1 + goff);
        }
        *(uint4*)asw0 = av0;
        *(uint4*)asw1 = av1;
        *(uint4*)bsw0 = bv0;
        *(uint4*)bsw1 = bv1;
        __syncthreads();

        short8 af[4], bf[4];
#pragma unroll
        for (int i = 0; i < 4; ++i) {
            af[i] = *(const short8*)(As + (wm * 64 + i * 16 + lr) * 32 + lq * 8);
            bf[i] = *(const short8*)(Bs + (wn * 64 + i * 16 + lr) * 32 + lq * 8);
        }
#pragma unroll
        for (int i = 0; i < 4; ++i)
#pragma unroll
            for (int j = 0; j < 4; ++j)
                acc[i][j] = __builtin_amdgcn_mfma_f32_16x16x32_bf16(
                    af[i], bf[j], acc[i][j], 0, 0, 0);
        __syncthreads();
        if (++tap == 9) { tap = 0; ++icb; }
    }

    // epilogue: C/D layout col=lane&15 (pixel), row=lq*4+reg (oc)
    const size_t outn = (size_t)n * 256 * 4096;
#pragma unroll
    for (int i = 0; i < 4; ++i) {
        int ocb = oc0 + wm * 64 + i * 16 + lq * 4;
#pragma unroll
        for (int j = 0; j < 4; ++j) {
            int po = pimg + wn * 64 + j * 16 + lr;
            float* op = out + outn + (size_t)ocb * 4096 + po;
#pragma unroll
            for (int r = 0; r < 4; ++r) op[(size_t)r * 4096] = acc[i][j][r];
        }
    }
}

extern "C" void kernel_launch(void* const* d_in, const int* in_sizes, int n_in,
                              void* d_out, int out_size, void* d_ws, size_t ws_size,
                              hipStream_t stream) {
    const float* x  = (const float*)d_in[0];   // 32*256*64*64
    const float* z  = (const float*)d_in[1];   // 256*64
    const float* W1 = (const float*)d_in[2];   // 16*64*64
    const float* B1 = (const float*)d_in[3];   // 16*64
    const float* W2 = (const float*)d_in[4];   // 16*144*64
    const float* B2 = (const float*)d_in[5];   // 16*144
    float* out = (float*)d_out;

    u16* xb = (u16*)d_ws;                       // 32*4096*256 bf16 = 64 MiB
    u16* wb = xb + (size_t)32 * 4096 * 256;     // 256*2304 bf16 = 1.125 MiB
    const size_t need = ((size_t)32 * 4096 * 256 + (size_t)256 * 2304) * 2;
    if (ws_size < need) return;  // ws too small for NHWC staging path

    nchw2nhwc<<<dim3(8192), dim3(256), 0, stream>>>(x, xb);
    wgen<<<dim3(256), dim3(256), 0, stream>>>(z, W1, B1, W2, B2, wb);
    conv_mfma<<<dim3(2048), dim3(256), 0, stream>>>(xb, wb, out);
}